// Round 5
// baseline (35717.361 us; speedup 1.0000x reference)
//
#include <hip/hip_runtime.h>
#include <hip/hip_fp16.h>

#define BB   64
#define TDEC 400
#define TENC 512
#define DD   256
#define PRE  128
#define NOUT 400
#define G3   768

typedef _Float16 h2_t __attribute__((ext_vector_type(2)));

// ---------------- fast math ----------------
__device__ __forceinline__ float fsig(float x) {
    return __builtin_amdgcn_rcpf(1.0f + __expf(-x));
}
__device__ __forceinline__ float ftanh(float x) {
    float t = __expf(2.0f * x);
    return 1.0f - 2.0f * __builtin_amdgcn_rcpf(t + 1.0f);
}
// 8-term fp16 x fp16 -> fp32 dot from two 16B packets
__device__ __forceinline__ float dot8(float4 w, float4 x, float acc) {
    union { float4 f; h2_t h[4]; } uw, ux;
    uw.f = w; ux.f = x;
#if __has_builtin(__builtin_amdgcn_fdot2)
    #pragma unroll
    for (int k = 0; k < 4; k++)
        acc = __builtin_amdgcn_fdot2(uw.h[k], ux.h[k], acc, false);
#else
    #pragma unroll
    for (int k = 0; k < 4; k++) {
        acc = fmaf((float)uw.h[k].x, (float)ux.h[k].x, acc);
        acc = fmaf((float)uw.h[k].y, (float)ux.h[k].y, acc);
    }
#endif
    return acc;
}

// ---------------- prenet ----------------
__global__ __launch_bounds__(256) void prenet_kernel(
    const float* __restrict__ x, const float* __restrict__ W1, const float* __restrict__ b1,
    const float* __restrict__ W2, const float* __restrict__ b2, __half* __restrict__ p_h)
{
    __shared__ __align__(16) float xs[8][NOUT];
    __shared__ __align__(16) float hs[8][DD];
    const int row0 = blockIdx.x * 8;
    const int tid = threadIdx.x;
    for (int idx = tid; idx < 8 * NOUT; idx += 256) {
        int m = idx / NOUT, i = idx - m * NOUT;
        xs[m][i] = x[(size_t)(row0 + m) * NOUT + i];
    }
    __syncthreads();
    {
        const int j = tid;
        float acc[8];
        float bj = b1[j];
        #pragma unroll
        for (int m = 0; m < 8; m++) acc[m] = bj;
        #pragma unroll 4
        for (int i = 0; i < NOUT; i++) {
            float w = W1[i * DD + j];
            #pragma unroll
            for (int m = 0; m < 8; m++) acc[m] = fmaf(xs[m][i], w, acc[m]);
        }
        #pragma unroll
        for (int m = 0; m < 8; m++) hs[m][j] = fmaxf(acc[m], 0.0f);
    }
    __syncthreads();
    if (tid < PRE) {
        const int j = tid;
        float acc[8];
        float bj = b2[j];
        #pragma unroll
        for (int m = 0; m < 8; m++) acc[m] = bj;
        #pragma unroll 4
        for (int i = 0; i < DD; i++) {
            float w = W2[i * PRE + j];
            #pragma unroll
            for (int m = 0; m < 8; m++) acc[m] = fmaf(hs[m][i], w, acc[m]);
        }
        #pragma unroll
        for (int m = 0; m < 8; m++)
            p_h[(size_t)(row0 + m) * PRE + j] = __float2half(fmaxf(acc[m], 0.0f));
    }
}

// ---------------- keys = fp16(memory @ Wm) ----------------
__global__ __launch_bounds__(256) void keys_kernel(
    const float* __restrict__ mem, const float* __restrict__ Wm, __half* __restrict__ keys_h)
{
    __shared__ __align__(16) float xs[8][DD];
    const int row0 = blockIdx.x * 8;
    const int tid = threadIdx.x;
    for (int idx = tid; idx < 8 * DD; idx += 256) {
        int m = idx >> 8, i = idx & 255;
        xs[m][i] = mem[(size_t)(row0 + m) * DD + i];
    }
    __syncthreads();
    const int j = tid;
    float acc[8] = {0.f,0.f,0.f,0.f,0.f,0.f,0.f,0.f};
    #pragma unroll 4
    for (int i = 0; i < DD; i++) {
        float w = Wm[i * DD + j];
        #pragma unroll
        for (int m = 0; m < 8; m++) acc[m] = fmaf(xs[m][i], w, acc[m]);
    }
    #pragma unroll
    for (int m = 0; m < 8; m++) keys_h[(size_t)(row0 + m) * DD + j] = __float2half(acc[m]);
}

// ---------------- 8-row pack: dst[(i8*C + j)*8 + k] = fp16 src[8*i8+k][j] ----------------
__global__ __launch_bounds__(256) void pack_w_kernel(
    const float* __restrict__ src, __half* __restrict__ dst, int R, int C)
{
    int flat = blockIdx.x * 256 + threadIdx.x;
    if (flat < R * C) {
        int k = flat & 7;
        int t2 = flat >> 3;
        int j = t2 % C;
        int i8 = t2 / C;
        dst[flat] = __float2half(src[(size_t)(8 * i8 + k) * C + j]);
    }
}

// ---- mem pack: dst[b*65536 + e2*256 + d] = {mem[b][2e2][d], mem[b][2e2+1][d]} ----
__global__ __launch_bounds__(256) void pack_mem_kernel(
    const float* __restrict__ mem, __half2* __restrict__ dst)
{
    int flat = blockIdx.x * 256 + threadIdx.x;
    if (flat < BB * 256 * 256) {
        int d  = flat & 255;
        int e2 = (flat >> 8) & 255;
        int b  = flat >> 16;
        const float* base = mem + ((size_t)b * TENC + 2 * e2) * DD + d;
        dst[flat] = __floats2half2_rn(base[0], base[DD]);
    }
}

// ---------------- y = ahist(fp16) @ Wo + bo ----------------
__global__ __launch_bounds__(448) void out_kernel(
    const __half* __restrict__ ah, const float* __restrict__ Wo, const float* __restrict__ bo,
    float* __restrict__ y)
{
    __shared__ __align__(16) float xs[8][DD];
    const int row0 = blockIdx.x * 8;
    const int tid = threadIdx.x;
    for (int idx = tid; idx < 8 * DD; idx += 448) {
        int m = idx >> 8, i = idx & 255;
        xs[m][i] = __half2float(ah[(size_t)(row0 + m) * DD + i]);
    }
    __syncthreads();
    if (tid < NOUT) {
        const int j = tid;
        float acc[8];
        float bj = bo[j];
        #pragma unroll
        for (int m = 0; m < 8; m++) acc[m] = bj;
        #pragma unroll 4
        for (int i = 0; i < DD; i++) {
            float w = Wo[i * NOUT + j];
            #pragma unroll
            for (int m = 0; m < 8; m++) acc[m] = fmaf(xs[m][i], w, acc[m]);
        }
        #pragma unroll
        for (int m = 0; m < 8; m++) y[(size_t)(row0 + m) * NOUT + j] = acc[m];
    }
}

// ---------------- decoder: 64 blocks (1/batch elem) x 768 threads ----------------
// GRU0 weights (k0: 48 fl4, r0: 32 fl4 per thread = 320 VGPRs) live in registers for
// all 400 steps -> GRU0 phase is stream-free. GRU1/Wq/Wa/keys/mem stream from L2.
// __launch_bounds__(768, 3): 1 block/CU intended, allow up to HW-max VGPRs.
__global__ __launch_bounds__(768, 3) void decoder_kernel(
    const __half* __restrict__ p_h,  const __half* __restrict__ keys_h,
    const __half2* __restrict__ mem_p,
    const __half* __restrict__ k0p,  const __half* __restrict__ r0p,
    const __half* __restrict__ k1p,  const __half* __restrict__ r1p,
    const __half* __restrict__ Wqp,  const __half* __restrict__ Wap,
    const float* __restrict__ bi0, const float* __restrict__ br0,
    const float* __restrict__ bi1, const float* __restrict__ br1,
    const float* __restrict__ v,   __half* __restrict__ ahist)
{
    __shared__ __align__(16) __half xa[384];            // [p_t(128) | att(256)]
    __shared__ __align__(16) __half h0s[DD], h1s[DD];   // fp16 state (dot operands)
    __shared__ __align__(16) __half vh[DD], qvh[2 * DD];
    __shared__ __align__(16) __half ins[2 * DD];        // [h1 | ctx]
    __shared__ __align__(16) float h0f[DD], h1f[DD];    // fp32 carry
    __shared__ __align__(16) float gx[G3], gh[G3];
    __shared__ __align__(16) float sc[TENC];            // exp(score)
    __shared__ __align__(16) float hWa[DD];             // h1 @ Wa_top
    __shared__ __align__(16) float qpart[DD * 4];
    __shared__ __align__(16) float cpart[DD * 4];
    __shared__ __align__(16) float apart[DD * 4];
    __shared__ float redd[16];
    __shared__ float sden[2];

    const int tid = threadIdx.x;
    const int b = blockIdx.x;
    const int d256 = tid & 255;          // 3-way split id
    const int third = tid >> 8;          // 0..2

    // ---- one-time: GRU0 weight slice -> registers (column tid) ----
    const float4* k0p4 = (const float4*)k0p;
    const float4* r0p4 = (const float4*)r0p;
    float4 wk0[48];
    float4 wr0[32];
    #pragma unroll
    for (int i = 0; i < 48; i++) wk0[i] = k0p4[(size_t)i * G3 + tid];
    #pragma unroll
    for (int i = 0; i < 32; i++) wr0[i] = r0p4[(size_t)i * G3 + tid];
    const float b0i_r = bi0[tid], b0r_r = br0[tid];
    const float b1i_r = bi1[tid], b1r_r = br1[tid];

    if (tid < DD) {
        vh[tid] = __float2half(v[tid]);
        h0f[tid] = 0.0f; h1f[tid] = 0.0f;
        h0s[tid] = __float2half(0.0f); h1s[tid] = __float2half(0.0f);
        xa[PRE + tid] = __float2half(0.0f);
    }
    __syncthreads();

    const float4*  Wqp4 = (const float4*)Wqp;
    const float4*  Wap4 = (const float4*)Wap;
    const float4*  k1p4 = (const float4*)k1p;
    const float4*  r1p4 = (const float4*)r1p;
    const __half*  keyb = keys_h + (size_t)b * TENC * DD;
    const __half2* memb = mem_p + (size_t)b * 256 * DD;
    const float4*  pb4  = (const float4*)(p_h + (size_t)b * TDEC * PRE);

    #pragma unroll 1
    for (int t = 0; t < TDEC; t++) {
        // ---- stage p_t ----
        if (tid < 16) ((float4*)xa)[tid] = pb4[t * 16 + tid];
        __syncthreads();   // S1: xa = [p_t | att_{t-1}] ready

        // ---- GRU0 (register weights, LDS inputs only) ----
        {
            const float4* xp4 = (const float4*)xa;
            const float4* hp4 = (const float4*)h0s;
            float acc = b0i_r, acc2 = b0r_r;
            #pragma unroll
            for (int i = 0; i < 32; i++) {
                acc  = dot8(wk0[i], xp4[i], acc);
                acc2 = dot8(wr0[i], hp4[i], acc2);
            }
            #pragma unroll
            for (int i = 32; i < 48; i++) acc = dot8(wk0[i], xp4[i], acc);
            gx[tid] = acc; gh[tid] = acc2;
        }
        __syncthreads();   // S2
        if (tid < DD) {
            float z = fsig(gx[tid] + gh[tid]);
            float r = fsig(gx[DD + tid] + gh[DD + tid]);
            float cand = ftanh(gx[2 * DD + tid] + r * gh[2 * DD + tid]);
            float hn = z * h0f[tid] + (1.0f - z) * cand;
            h0f[tid] = hn; h0s[tid] = __float2half(hn);
        }
        __syncthreads();   // S3

        // ---- GRU1 (streamed k1/r1, merged dual chains) ----
        {
            const float4* hp0 = (const float4*)h0s;
            const float4* hp1 = (const float4*)h1s;
            float acc = b1i_r, acc2 = b1r_r;
            #pragma unroll 4
            for (int i = 0; i < 32; i++) {
                acc  = dot8(k1p4[(size_t)i * G3 + tid], hp0[i], acc);
                acc2 = dot8(r1p4[(size_t)i * G3 + tid], hp1[i], acc2);
            }
            gx[tid] = acc; gh[tid] = acc2;
        }
        __syncthreads();   // S4
        if (tid < DD) {
            float z = fsig(gx[tid] + gh[tid]);
            float r = fsig(gx[DD + tid] + gh[DD + tid]);
            float cand = ftanh(gx[2 * DD + tid] + r * gh[2 * DD + tid]);
            float hn = z * h1f[tid] + (1.0f - z) * cand;
            h1f[tid] = hn;
            __half hh = __float2half(hn);
            h1s[tid] = hh;
            ins[tid] = hh;            // [h1 | ctx] first half
        }
        __syncthreads();   // S5

        // ---- q = h1 @ Wq : 768 threads = 256 cols x 3 K-chunks ----
        {
            const float4* hp4 = (const float4*)h1s;
            int i8b = third * 11;
            int cnt = (third == 2) ? 10 : 11;
            float acc = 0.0f;
            #pragma unroll 4
            for (int i = 0; i < cnt; i++)
                acc = dot8(Wqp4[(size_t)(i8b + i) * DD + d256], hp4[i8b + i], acc);
            qpart[d256 * 4 + third] = acc;
        }
        __syncthreads();   // S6
        if (tid < DD) {
            float qf = qpart[tid * 4] + qpart[tid * 4 + 1] + qpart[tid * 4 + 2];
            qvh[2 * tid] = __float2half(qf);
            qvh[2 * tid + 1] = vh[tid];
        }
        __syncthreads();   // S7

        // ---- scores (512 thr, e-rows) + hWa = h1 @ Wa_top (256 thr) ----
        if (tid < TENC) {
            const float4* kp = (const float4*)(keyb + (size_t)tid * DD);
            const float4* qp = (const float4*)qvh;
            float s = 0.0f;
            #pragma unroll 4
            for (int i8 = 0; i8 < 32; i8++) {
                union { float4 f; h2_t h[4]; } uk, u0, u1;
                uk.f = kp[i8]; u0.f = qp[2 * i8]; u1.f = qp[2 * i8 + 1];
                s = fmaf((float)u0.h[0].y, ftanh((float)uk.h[0].x + (float)u0.h[0].x), s);
                s = fmaf((float)u0.h[1].y, ftanh((float)uk.h[0].y + (float)u0.h[1].x), s);
                s = fmaf((float)u0.h[2].y, ftanh((float)uk.h[1].x + (float)u0.h[2].x), s);
                s = fmaf((float)u0.h[3].y, ftanh((float)uk.h[1].y + (float)u0.h[3].x), s);
                s = fmaf((float)u1.h[0].y, ftanh((float)uk.h[2].x + (float)u1.h[0].x), s);
                s = fmaf((float)u1.h[1].y, ftanh((float)uk.h[2].y + (float)u1.h[1].x), s);
                s = fmaf((float)u1.h[2].y, ftanh((float)uk.h[3].x + (float)u1.h[2].x), s);
                s = fmaf((float)u1.h[3].y, ftanh((float)uk.h[3].y + (float)u1.h[3].x), s);
            }
            float wv = __expf(s);   // |s| bounded by sum|v| ~ 11; fp32-safe
            sc[tid] = wv;
            #pragma unroll
            for (int off = 32; off; off >>= 1) wv += __shfl_down(wv, off);
            if ((tid & 63) == 0) redd[tid >> 6] = wv;
        } else {
            const int dd = tid - TENC;
            const float4* hp4 = (const float4*)h1s;
            float acc = 0.0f;
            #pragma unroll 4
            for (int i8 = 0; i8 < 32; i8++)
                acc = dot8(Wap4[(size_t)i8 * DD + dd], hp4[i8], acc);
            hWa[dd] = acc;
        }
        __syncthreads();   // S8

        // ---- ctx partials (768 thr = 256 d x 3 e-chunks) + den total (thr 0) ----
        {
            int e2b = (third == 0) ? 0 : (third == 1 ? 86 : 171);
            int e2e = (third == 0) ? 86 : (third == 1 ? 171 : 256);
            const __half2* mp = memb + d256;
            float acc = 0.0f;
            #pragma unroll 4
            for (int e2 = e2b; e2 < e2e; e2++) {
                float2 f = __half22float2(mp[(size_t)e2 * DD]);
                acc = fmaf(f.x, sc[2 * e2], acc);
                acc = fmaf(f.y, sc[2 * e2 + 1], acc);
            }
            cpart[d256 * 4 + third] = acc;
        }
        if (tid == 0) {
            float ssum = 0.0f;
            #pragma unroll
            for (int i = 0; i < 8; i++) ssum += redd[i];
            sden[0] = ssum;
        }
        __syncthreads();   // S9
        if (tid < DD) {
            float invS = __builtin_amdgcn_rcpf(sden[0]);
            float cx = (cpart[tid * 4] + cpart[tid * 4 + 1] + cpart[tid * 4 + 2]) * invS;
            ins[DD + tid] = __float2half(cx);
        }
        __syncthreads();   // S10

        // ---- attn bottom: ctx-rows of Wa (i8 32..63), 256 cols x 3 K-chunks ----
        {
            const float4* ip4 = (const float4*)ins;
            int i8b = 32 + third * 11;
            int cnt = (third == 2) ? 10 : 11;
            float acc = 0.0f;
            #pragma unroll 4
            for (int i = 0; i < cnt; i++)
                acc = dot8(Wap4[(size_t)(i8b + i) * DD + d256], ip4[i8b + i], acc);
            apart[d256 * 4 + third] = acc;
        }
        __syncthreads();   // S11
        if (tid < DD) {
            float av = hWa[tid] + apart[tid * 4] + apart[tid * 4 + 1] + apart[tid * 4 + 2];
            __half ah = __float2half(av);
            xa[PRE + tid] = ah;
            ahist[((size_t)b * TDEC + t) * DD + tid] = ah;
        }
        __syncthreads();   // S12 (protects xa before next p-stage)
    }
}

extern "C" void kernel_launch(void* const* d_in, const int* in_sizes, int n_in,
                              void* d_out, int out_size, void* d_ws, size_t ws_size,
                              hipStream_t stream)
{
    const float* dec    = (const float*)d_in[0];
    const float* memory = (const float*)d_in[1];
    const float* W1  = (const float*)d_in[2];
    const float* b1  = (const float*)d_in[3];
    const float* W2  = (const float*)d_in[4];
    const float* b2  = (const float*)d_in[5];
    const float* k0  = (const float*)d_in[6];
    const float* r0  = (const float*)d_in[7];
    const float* bi0 = (const float*)d_in[8];
    const float* br0 = (const float*)d_in[9];
    const float* k1  = (const float*)d_in[10];
    const float* r1  = (const float*)d_in[11];
    const float* bi1 = (const float*)d_in[12];
    const float* br1 = (const float*)d_in[13];
    const float* Wq  = (const float*)d_in[14];
    const float* Wm  = (const float*)d_in[15];
    const float* v   = (const float*)d_in[16];
    const float* Wa  = (const float*)d_in[17];
    const float* Wo  = (const float*)d_in[18];
    const float* bo  = (const float*)d_in[19];
    float* out = (float*)d_out;
    (void)ws_size; (void)in_sizes; (void)n_in; (void)out_size;

    // ---- workspace layout (fp16 packs) ----
    char* w = (char*)d_ws;
    size_t off = 0;
    __half*  p_h    = (__half*)(w + off);  off += (size_t)BB * TDEC * PRE * 2;
    __half*  keys_h = (__half*)(w + off);  off += (size_t)BB * TENC * DD * 2;
    __half2* mem_p  = (__half2*)(w + off); off += (size_t)BB * TENC * DD * 2;
    __half*  k0p    = (__half*)(w + off);  off += (size_t)384 * G3 * 2;
    __half*  r0p    = (__half*)(w + off);  off += (size_t)DD * G3 * 2;
    __half*  k1p    = (__half*)(w + off);  off += (size_t)DD * G3 * 2;
    __half*  r1p    = (__half*)(w + off);  off += (size_t)DD * G3 * 2;
    __half*  Wqp    = (__half*)(w + off);  off += (size_t)DD * DD * 2;
    __half*  Wap    = (__half*)(w + off);  off += (size_t)2 * DD * DD * 2;
    __half*  ahist  = (__half*)(w + off);  off += (size_t)BB * TDEC * DD * 2;

    // precompute (parallel, outside the recurrence)
    prenet_kernel<<<BB * TDEC / 8, 256, 0, stream>>>(dec, W1, b1, W2, b2, p_h);
    keys_kernel<<<BB * TENC / 8, 256, 0, stream>>>(memory, Wm, keys_h);
    pack_mem_kernel<<<(BB * 256 * 256) / 256, 256, 0, stream>>>(memory, mem_p);
    pack_w_kernel<<<(384 * G3 + 255) / 256, 256, 0, stream>>>(k0, k0p, 384, G3);
    pack_w_kernel<<<(DD * G3 + 255) / 256, 256, 0, stream>>>(r0, r0p, DD, G3);
    pack_w_kernel<<<(DD * G3 + 255) / 256, 256, 0, stream>>>(k1, k1p, DD, G3);
    pack_w_kernel<<<(DD * G3 + 255) / 256, 256, 0, stream>>>(r1, r1p, DD, G3);
    pack_w_kernel<<<(DD * DD + 255) / 256, 256, 0, stream>>>(Wq, Wqp, DD, DD);
    pack_w_kernel<<<(2 * DD * DD + 255) / 256, 256, 0, stream>>>(Wa, Wap, 2 * DD, DD);

    // the 400-step recurrence: 1 block/batch elem, GRU0 weights register-resident
    decoder_kernel<<<BB, 768, 0, stream>>>(p_h, keys_h, mem_p, k0p, r0p, k1p, r1p,
                                           Wqp, Wap, bi0, br0, bi1, br1, v, ahist);

    // output projection (outside the recurrence)
    out_kernel<<<BB * TDEC / 8, 448, 0, stream>>>(ahist, Wo, bo, out);
}

// Round 6
// 23252.419 us; speedup vs baseline: 1.5361x; 1.5361x over previous
//
#include <hip/hip_runtime.h>
#include <hip/hip_fp16.h>

#define BB   64
#define TDEC 400
#define TENC 512
#define DD   256
#define PRE  128
#define NOUT 400
#define G3   768

typedef _Float16 h2_t __attribute__((ext_vector_type(2)));

// ---------------- fast math ----------------
__device__ __forceinline__ float fsig(float x) {
    return __builtin_amdgcn_rcpf(1.0f + __expf(-x));
}
__device__ __forceinline__ float ftanh(float x) {
    float t = __expf(2.0f * x);
    return 1.0f - 2.0f * __builtin_amdgcn_rcpf(t + 1.0f);
}
// 8-term fp16 x fp16 -> fp32 dot from two 16B packets
__device__ __forceinline__ float dot8(float4 w, float4 x, float acc) {
    union { float4 f; h2_t h[4]; } uw, ux;
    uw.f = w; ux.f = x;
#if __has_builtin(__builtin_amdgcn_fdot2)
    #pragma unroll
    for (int k = 0; k < 4; k++)
        acc = __builtin_amdgcn_fdot2(uw.h[k], ux.h[k], acc, false);
#else
    #pragma unroll
    for (int k = 0; k < 4; k++) {
        acc = fmaf((float)uw.h[k].x, (float)ux.h[k].x, acc);
        acc = fmaf((float)uw.h[k].y, (float)ux.h[k].y, acc);
    }
#endif
    return acc;
}

// ---------------- prenet ----------------
__global__ __launch_bounds__(256) void prenet_kernel(
    const float* __restrict__ x, const float* __restrict__ W1, const float* __restrict__ b1,
    const float* __restrict__ W2, const float* __restrict__ b2, __half* __restrict__ p_h)
{
    __shared__ __align__(16) float xs[8][NOUT];
    __shared__ __align__(16) float hs[8][DD];
    const int row0 = blockIdx.x * 8;
    const int tid = threadIdx.x;
    for (int idx = tid; idx < 8 * NOUT; idx += 256) {
        int m = idx / NOUT, i = idx - m * NOUT;
        xs[m][i] = x[(size_t)(row0 + m) * NOUT + i];
    }
    __syncthreads();
    {
        const int j = tid;
        float acc[8];
        float bj = b1[j];
        #pragma unroll
        for (int m = 0; m < 8; m++) acc[m] = bj;
        #pragma unroll 4
        for (int i = 0; i < NOUT; i++) {
            float w = W1[i * DD + j];
            #pragma unroll
            for (int m = 0; m < 8; m++) acc[m] = fmaf(xs[m][i], w, acc[m]);
        }
        #pragma unroll
        for (int m = 0; m < 8; m++) hs[m][j] = fmaxf(acc[m], 0.0f);
    }
    __syncthreads();
    if (tid < PRE) {
        const int j = tid;
        float acc[8];
        float bj = b2[j];
        #pragma unroll
        for (int m = 0; m < 8; m++) acc[m] = bj;
        #pragma unroll 4
        for (int i = 0; i < DD; i++) {
            float w = W2[i * PRE + j];
            #pragma unroll
            for (int m = 0; m < 8; m++) acc[m] = fmaf(hs[m][i], w, acc[m]);
        }
        #pragma unroll
        for (int m = 0; m < 8; m++)
            p_h[(size_t)(row0 + m) * PRE + j] = __float2half(fmaxf(acc[m], 0.0f));
    }
}

// ---------------- keys = fp16(memory @ Wm) ----------------
__global__ __launch_bounds__(256) void keys_kernel(
    const float* __restrict__ mem, const float* __restrict__ Wm, __half* __restrict__ keys_h)
{
    __shared__ __align__(16) float xs[8][DD];
    const int row0 = blockIdx.x * 8;
    const int tid = threadIdx.x;
    for (int idx = tid; idx < 8 * DD; idx += 256) {
        int m = idx >> 8, i = idx & 255;
        xs[m][i] = mem[(size_t)(row0 + m) * DD + i];
    }
    __syncthreads();
    const int j = tid;
    float acc[8] = {0.f,0.f,0.f,0.f,0.f,0.f,0.f,0.f};
    #pragma unroll 4
    for (int i = 0; i < DD; i++) {
        float w = Wm[i * DD + j];
        #pragma unroll
        for (int m = 0; m < 8; m++) acc[m] = fmaf(xs[m][i], w, acc[m]);
    }
    #pragma unroll
    for (int m = 0; m < 8; m++) keys_h[(size_t)(row0 + m) * DD + j] = __float2half(acc[m]);
}

// ---------------- 8-row pack: dst[(i8*C + j)*8 + k] = fp16 src[8*i8+k][j] ----------------
__global__ __launch_bounds__(256) void pack_w_kernel(
    const float* __restrict__ src, __half* __restrict__ dst, int R, int C)
{
    int flat = blockIdx.x * 256 + threadIdx.x;
    if (flat < R * C) {
        int k = flat & 7;
        int t2 = flat >> 3;
        int j = t2 % C;
        int i8 = t2 / C;
        dst[flat] = __float2half(src[(size_t)(8 * i8 + k) * C + j]);
    }
}

// ---- mem pack: dst[b*65536 + e2*256 + d] = {mem[b][2e2][d], mem[b][2e2+1][d]} ----
__global__ __launch_bounds__(256) void pack_mem_kernel(
    const float* __restrict__ mem, __half2* __restrict__ dst)
{
    int flat = blockIdx.x * 256 + threadIdx.x;
    if (flat < BB * 256 * 256) {
        int d  = flat & 255;
        int e2 = (flat >> 8) & 255;
        int b  = flat >> 16;
        const float* base = mem + ((size_t)b * TENC + 2 * e2) * DD + d;
        dst[flat] = __floats2half2_rn(base[0], base[DD]);
    }
}

// ---- pregx: gxp[(row)*768 + c] = fp16( bi0[c] + p[row,:] @ k0[0:128,:] ), 32 rows/block ----
__global__ __launch_bounds__(768) void pregx_kernel(
    const __half* __restrict__ p_h, const __half* __restrict__ k0t,
    const float* __restrict__ bi0, __half* __restrict__ gxp)
{
    __shared__ __align__(16) float4 xs4[32 * 16];   // 32 rows x 128 halves
    const int tid = threadIdx.x;
    const int row0 = blockIdx.x * 32;
    if (tid < 512) {
        int r = tid >> 4, i8 = tid & 15;
        xs4[r * 16 + i8] = ((const float4*)(p_h + (size_t)(row0 + r) * PRE))[i8];
    }
    __syncthreads();
    const int c = tid;
    const float4* wp = (const float4*)k0t;
    float acc[32];
    #pragma unroll
    for (int r = 0; r < 32; r++) acc[r] = 0.0f;
    for (int i8 = 0; i8 < 16; i8++) {
        float4 wv = wp[(size_t)i8 * G3 + c];
        #pragma unroll
        for (int r = 0; r < 32; r++) acc[r] = dot8(wv, xs4[r * 16 + i8], acc[r]);
    }
    const float bc = bi0[c];
    #pragma unroll 4
    for (int r = 0; r < 32; r++)
        gxp[(size_t)(row0 + r) * G3 + c] = __float2half(acc[r] + bc);
}

// ---------------- y = ahist(fp16) @ Wo + bo ----------------
__global__ __launch_bounds__(448) void out_kernel(
    const __half* __restrict__ ah, const float* __restrict__ Wo, const float* __restrict__ bo,
    float* __restrict__ y)
{
    __shared__ __align__(16) float xs[8][DD];
    const int row0 = blockIdx.x * 8;
    const int tid = threadIdx.x;
    for (int idx = tid; idx < 8 * DD; idx += 448) {
        int m = idx >> 8, i = idx & 255;
        xs[m][i] = __half2float(ah[(size_t)(row0 + m) * DD + i]);
    }
    __syncthreads();
    if (tid < NOUT) {
        const int j = tid;
        float acc[8];
        float bj = bo[j];
        #pragma unroll
        for (int m = 0; m < 8; m++) acc[m] = bj;
        #pragma unroll 4
        for (int i = 0; i < DD; i++) {
            float w = Wo[i * NOUT + j];
            #pragma unroll
            for (int m = 0; m < 8; m++) acc[m] = fmaf(xs[m][i], w, acc[m]);
        }
        #pragma unroll
        for (int m = 0; m < 8; m++) y[(size_t)(row0 + m) * NOUT + j] = acc[m];
    }
}

// ---------------- decoder: 64 blocks (1/batch elem) x 768 threads ----------------
// p@k0_top hoisted (gxp). Phase 1 runs three concurrent weight streams
// (k0_att, r0, r1); q/ctx/attn-bottom use all 768 threads (3-way splits).
__global__ __launch_bounds__(768) void decoder_kernel(
    const __half* __restrict__ gxp,  const __half* __restrict__ keys_h,
    const __half2* __restrict__ mem_p,
    const __half* __restrict__ k0a,  const __half* __restrict__ r0p,
    const __half* __restrict__ k1p,  const __half* __restrict__ r1p,
    const __half* __restrict__ Wqp,  const __half* __restrict__ Wap,
    const float* __restrict__ br0,
    const float* __restrict__ bi1, const float* __restrict__ br1,
    const float* __restrict__ v,   __half* __restrict__ ahist)
{
    __shared__ __align__(16) __half atth[DD];           // att_{t-1} fp16
    __shared__ __align__(16) __half h0s[DD], h1s[DD];   // fp16 state (dot operands)
    __shared__ __align__(16) __half vh[DD], qvh[2 * DD];
    __shared__ __align__(16) __half ins[2 * DD];        // [h1 | ctx]
    __shared__ __align__(16) float h0f[DD], h1f[DD];    // fp32 carry
    __shared__ __align__(16) float gx[G3], gh[G3], gh1[G3];
    __shared__ __align__(16) float sc[TENC];            // exp(score)
    __shared__ __align__(16) float hWa[DD];             // h1 @ Wa_top
    __shared__ __align__(16) float qpart[DD * 4];
    __shared__ __align__(16) float cpart[DD * 4];
    __shared__ __align__(16) float apart[DD * 4];
    __shared__ float redd[16];
    __shared__ float sden[2];

    const int tid = threadIdx.x;
    const int b = blockIdx.x;
    const int d256 = tid & 255;
    const int third = tid >> 8;

    const float b0r_r = br0[tid];
    const float b1i_r = bi1[tid];
    const float b1r_r = br1[tid];

    if (tid < DD) {
        vh[tid] = __float2half(v[tid]);
        h0f[tid] = 0.0f; h1f[tid] = 0.0f;
        h0s[tid] = __float2half(0.0f); h1s[tid] = __float2half(0.0f);
        atth[tid] = __float2half(0.0f);
    }
    __syncthreads();

    const float4*  k0a4 = (const float4*)k0a;
    const float4*  r0p4 = (const float4*)r0p;
    const float4*  k1p4 = (const float4*)k1p;
    const float4*  r1p4 = (const float4*)r1p;
    const float4*  Wqp4 = (const float4*)Wqp;
    const float4*  Wap4 = (const float4*)Wap;
    const __half*  keyb = keys_h + (size_t)b * TENC * DD;
    const __half2* memb = mem_p + (size_t)b * 256 * DD;
    const __half*  gxpb = gxp + (size_t)b * TDEC * G3;

    #pragma unroll 1
    for (int t = 0; t < TDEC; t++) {
        // ---- P1: three concurrent streams: gx0 = pre + att@k0a ; gh0 = h0@r0 ; gh1 = h1@r1
        {
            const float4* ap4 = (const float4*)atth;
            const float4* h04 = (const float4*)h0s;
            const float4* h14 = (const float4*)h1s;
            float acc = __half2float(gxpb[(size_t)t * G3 + tid]);
            float ac0 = b0r_r;
            float ac1 = b1r_r;
            #pragma unroll 4
            for (int i8 = 0; i8 < 32; i8++) {
                acc = dot8(k0a4[(size_t)i8 * G3 + tid], ap4[i8], acc);
                ac0 = dot8(r0p4[(size_t)i8 * G3 + tid], h04[i8], ac0);
                ac1 = dot8(r1p4[(size_t)i8 * G3 + tid], h14[i8], ac1);
            }
            gx[tid] = acc; gh[tid] = ac0; gh1[tid] = ac1;
        }
        __syncthreads();   // A
        // ---- P2: GRU0 combine ----
        if (tid < DD) {
            float z = fsig(gx[tid] + gh[tid]);
            float r = fsig(gx[DD + tid] + gh[DD + tid]);
            float cand = ftanh(gx[2 * DD + tid] + r * gh[2 * DD + tid]);
            float hn = z * h0f[tid] + (1.0f - z) * cand;
            h0f[tid] = hn; h0s[tid] = __float2half(hn);
        }
        __syncthreads();   // B
        // ---- P3: gx1 = bi1 + h0n @ k1 ----
        {
            const float4* h04 = (const float4*)h0s;
            float acc = b1i_r;
            #pragma unroll 4
            for (int i8 = 0; i8 < 32; i8++)
                acc = dot8(k1p4[(size_t)i8 * G3 + tid], h04[i8], acc);
            gx[tid] = acc;
        }
        __syncthreads();   // C
        // ---- P4: GRU1 combine ----
        if (tid < DD) {
            float z = fsig(gx[tid] + gh1[tid]);
            float r = fsig(gx[DD + tid] + gh1[DD + tid]);
            float cand = ftanh(gx[2 * DD + tid] + r * gh1[2 * DD + tid]);
            float hn = z * h1f[tid] + (1.0f - z) * cand;
            h1f[tid] = hn;
            __half hh = __float2half(hn);
            h1s[tid] = hh;
            ins[tid] = hh;
        }
        __syncthreads();   // D
        // ---- P5: q partials (768 thr = 256 cols x 3 K-chunks) ----
        {
            const float4* hp4 = (const float4*)h1s;
            int i8b = third * 11;
            int cnt = (third == 2) ? 10 : 11;
            float acc = 0.0f;
            #pragma unroll 4
            for (int i = 0; i < cnt; i++)
                acc = dot8(Wqp4[(size_t)(i8b + i) * DD + d256], hp4[i8b + i], acc);
            qpart[d256 * 4 + third] = acc;
        }
        __syncthreads();   // E
        // ---- P6: q finalize ----
        if (tid < DD) {
            float qf = qpart[tid * 4] + qpart[tid * 4 + 1] + qpart[tid * 4 + 2];
            qvh[2 * tid] = __float2half(qf);
            qvh[2 * tid + 1] = vh[tid];
        }
        __syncthreads();   // F
        // ---- P7: scores (512 thr) + hWa = h1 @ Wa_top (256 thr) ----
        if (tid < TENC) {
            const float4* kp = (const float4*)(keyb + (size_t)tid * DD);
            const float4* qp = (const float4*)qvh;
            float s = 0.0f;
            #pragma unroll 4
            for (int i8 = 0; i8 < 32; i8++) {
                union { float4 f; h2_t h[4]; } uk, u0, u1;
                uk.f = kp[i8]; u0.f = qp[2 * i8]; u1.f = qp[2 * i8 + 1];
                s = fmaf((float)u0.h[0].y, ftanh((float)uk.h[0].x + (float)u0.h[0].x), s);
                s = fmaf((float)u0.h[1].y, ftanh((float)uk.h[0].y + (float)u0.h[1].x), s);
                s = fmaf((float)u0.h[2].y, ftanh((float)uk.h[1].x + (float)u0.h[2].x), s);
                s = fmaf((float)u0.h[3].y, ftanh((float)uk.h[1].y + (float)u0.h[3].x), s);
                s = fmaf((float)u1.h[0].y, ftanh((float)uk.h[2].x + (float)u1.h[0].x), s);
                s = fmaf((float)u1.h[1].y, ftanh((float)uk.h[2].y + (float)u1.h[1].x), s);
                s = fmaf((float)u1.h[2].y, ftanh((float)uk.h[3].x + (float)u1.h[2].x), s);
                s = fmaf((float)u1.h[3].y, ftanh((float)uk.h[3].y + (float)u1.h[3].x), s);
            }
            float wv = __expf(s);
            sc[tid] = wv;
            #pragma unroll
            for (int off = 32; off; off >>= 1) wv += __shfl_down(wv, off);
            if ((tid & 63) == 0) redd[tid >> 6] = wv;
        } else {
            const int dd = tid - TENC;
            const float4* hp4 = (const float4*)h1s;
            float acc = 0.0f;
            #pragma unroll 4
            for (int i8 = 0; i8 < 32; i8++)
                acc = dot8(Wap4[(size_t)i8 * DD + dd], hp4[i8], acc);
            hWa[dd] = acc;
        }
        __syncthreads();   // G
        // ---- P8: ctx partials (3-way over e) + den total ----
        {
            int e2b = (third == 0) ? 0 : (third == 1 ? 86 : 171);
            int e2e = (third == 0) ? 86 : (third == 1 ? 171 : 256);
            const __half2* mp = memb + d256;
            float acc = 0.0f;
            #pragma unroll 4
            for (int e2 = e2b; e2 < e2e; e2++) {
                float2 f = __half22float2(mp[(size_t)e2 * DD]);
                acc = fmaf(f.x, sc[2 * e2], acc);
                acc = fmaf(f.y, sc[2 * e2 + 1], acc);
            }
            cpart[d256 * 4 + third] = acc;
        }
        if (tid == 0) {
            float ssum = 0.0f;
            #pragma unroll
            for (int i = 0; i < 8; i++) ssum += redd[i];
            sden[0] = ssum;
        }
        __syncthreads();   // H
        // ---- P9: ctx finalize ----
        if (tid < DD) {
            float invS = __builtin_amdgcn_rcpf(sden[0]);
            float cx = (cpart[tid * 4] + cpart[tid * 4 + 1] + cpart[tid * 4 + 2]) * invS;
            ins[DD + tid] = __float2half(cx);
        }
        __syncthreads();   // I
        // ---- P10: attn-bottom partials (3-way over K) ----
        {
            const float4* ip4 = (const float4*)ins;
            int i8b = 32 + third * 11;
            int cnt = (third == 2) ? 10 : 11;
            float acc = 0.0f;
            #pragma unroll 4
            for (int i = 0; i < cnt; i++)
                acc = dot8(Wap4[(size_t)(i8b + i) * DD + d256], ip4[i8b + i], acc);
            apart[d256 * 4 + third] = acc;
        }
        __syncthreads();   // J
        // ---- P11: attn finalize -> carry + history ----
        if (tid < DD) {
            float av = hWa[tid] + apart[tid * 4] + apart[tid * 4 + 1] + apart[tid * 4 + 2];
            __half ah = __float2half(av);
            atth[tid] = ah;
            ahist[((size_t)b * TDEC + t) * DD + tid] = ah;
        }
        __syncthreads();   // K (protects atth/ins for next P1)
    }
}

extern "C" void kernel_launch(void* const* d_in, const int* in_sizes, int n_in,
                              void* d_out, int out_size, void* d_ws, size_t ws_size,
                              hipStream_t stream)
{
    const float* dec    = (const float*)d_in[0];
    const float* memory = (const float*)d_in[1];
    const float* W1  = (const float*)d_in[2];
    const float* b1  = (const float*)d_in[3];
    const float* W2  = (const float*)d_in[4];
    const float* b2  = (const float*)d_in[5];
    const float* k0  = (const float*)d_in[6];
    const float* r0  = (const float*)d_in[7];
    const float* bi0 = (const float*)d_in[8];
    const float* br0 = (const float*)d_in[9];
    const float* k1  = (const float*)d_in[10];
    const float* r1  = (const float*)d_in[11];
    const float* bi1 = (const float*)d_in[12];
    const float* br1 = (const float*)d_in[13];
    const float* Wq  = (const float*)d_in[14];
    const float* Wm  = (const float*)d_in[15];
    const float* v   = (const float*)d_in[16];
    const float* Wa  = (const float*)d_in[17];
    const float* Wo  = (const float*)d_in[18];
    const float* bo  = (const float*)d_in[19];
    float* out = (float*)d_out;
    (void)ws_size; (void)in_sizes; (void)n_in; (void)out_size;

    // ---- workspace layout (fp16 packs) ----
    char* w = (char*)d_ws;
    size_t off = 0;
    __half*  p_h    = (__half*)(w + off);  off += (size_t)BB * TDEC * PRE * 2;   // 6.55 MB
    __half*  keys_h = (__half*)(w + off);  off += (size_t)BB * TENC * DD * 2;    // 16.8 MB
    __half2* mem_p  = (__half2*)(w + off); off += (size_t)BB * TENC * DD * 2;    // 16.8 MB
    __half*  k0t    = (__half*)(w + off);  off += (size_t)PRE * G3 * 2;          // 196 KB (k0 rows 0..127)
    __half*  k0a    = (__half*)(w + off);  off += (size_t)DD * G3 * 2;           // 393 KB (k0 rows 128..383)
    __half*  r0p    = (__half*)(w + off);  off += (size_t)DD * G3 * 2;
    __half*  k1p    = (__half*)(w + off);  off += (size_t)DD * G3 * 2;
    __half*  r1p    = (__half*)(w + off);  off += (size_t)DD * G3 * 2;
    __half*  Wqp    = (__half*)(w + off);  off += (size_t)DD * DD * 2;
    __half*  Wap    = (__half*)(w + off);  off += (size_t)2 * DD * DD * 2;
    __half*  gxp    = (__half*)(w + off);  off += (size_t)BB * TDEC * G3 * 2;    // 39.3 MB
    __half*  ahist  = (__half*)(w + off);  off += (size_t)BB * TDEC * DD * 2;    // 13.1 MB

    // precompute (parallel, outside the recurrence)
    prenet_kernel<<<BB * TDEC / 8, 256, 0, stream>>>(dec, W1, b1, W2, b2, p_h);
    keys_kernel<<<BB * TENC / 8, 256, 0, stream>>>(memory, Wm, keys_h);
    pack_mem_kernel<<<(BB * 256 * 256) / 256, 256, 0, stream>>>(memory, mem_p);
    pack_w_kernel<<<(PRE * G3 + 255) / 256, 256, 0, stream>>>(k0, k0t, PRE, G3);
    pack_w_kernel<<<(DD * G3 + 255) / 256, 256, 0, stream>>>(k0 + (size_t)PRE * G3, k0a, DD, G3);
    pack_w_kernel<<<(DD * G3 + 255) / 256, 256, 0, stream>>>(r0, r0p, DD, G3);
    pack_w_kernel<<<(DD * G3 + 255) / 256, 256, 0, stream>>>(k1, k1p, DD, G3);
    pack_w_kernel<<<(DD * G3 + 255) / 256, 256, 0, stream>>>(r1, r1p, DD, G3);
    pack_w_kernel<<<(DD * DD + 255) / 256, 256, 0, stream>>>(Wq, Wqp, DD, DD);
    pack_w_kernel<<<(2 * DD * DD + 255) / 256, 256, 0, stream>>>(Wa, Wap, 2 * DD, DD);
    // hoisted p @ k0_top + bi0 (depends on p_h)
    pregx_kernel<<<BB * TDEC / 32, 768, 0, stream>>>(p_h, k0t, bi0, gxp);

    // the 400-step recurrence: 1 block/batch elem, no cross-block sync
    decoder_kernel<<<BB, 768, 0, stream>>>(gxp, keys_h, mem_p, k0a, r0p, k1p, r1p,
                                           Wqp, Wap, br0, bi1, br1, v, ahist);

    // output projection (outside the recurrence)
    out_kernel<<<BB * TDEC / 8, 448, 0, stream>>>(ahist, Wo, bo, out);
}